// Round 6
// baseline (112.077 us; speedup 1.0000x reference)
//
#include <hip/hip_runtime.h>
#include <math.h>

// Problem constants (match reference)
constexpr int V = 131072;   // vocab / leaves
constexpr int D = 17;       // tree depth
constexpr int B = 16384;    // batch
constexpr int E = 128;      // embedding dim

constexpr int LPG  = 32;                  // lanes per sample group
constexpr int SPB  = 8;                   // samples per block (256 threads / 32)
constexpr int NBLK = B / SPB;             // 2048 blocks -> 8192 waves (vs 4096)

// 32 lanes per sample (1 float4 of the row per lane), 2 samples per wave.
// Doubles resident wave count vs the 16-lane layout (kernel is latency-bound:
// VALU ~10% busy, FETCH at the 33 MB unique floor) and makes every W-row read
// a single sequential 512 B burst. __launch_bounds__(256,6) caps VGPRs ~85 —
// deep load pipelining without spills, 24 waves/CU.
__global__ __launch_bounds__(256, 6) void hsm_main(
    const float* __restrict__ emb,
    const int*   __restrict__ widx,
    const float* __restrict__ W,
    const float* __restrict__ bias,
    float*       __restrict__ partial)
{
    const int lane = threadIdx.x & 63;
    const int wid  = threadIdx.x >> 6;
    const int g    = lane >> 5;            // subgroup 0..1 within wave
    const int l    = lane & 31;            // lane within subgroup
    const int b    = blockIdx.x * SPB + wid * 2 + g;

    // embedding row: 32 lanes x 1 float4 = 512 B, register-cached
    const float4 e0 = ((const float4*)(emb + (size_t)b * E))[l];

    const int j0 = widx[b] + V;            // 1-indexed leaf in heap layout

    float loss = 0.0f;
    #pragma unroll
    for (int d = 0; d < D; ++d) {
        const int   jc   = j0 >> d;        // 1-indexed child at this step
        const int   node = (jc >> 1) - 1;  // 0-indexed parent (scored node)
        const float t    = (float)(1 - (jc & 1));

        const float4 w0 = ((const float4*)(W + (size_t)node * E))[l];

        float p;
        p = fmaf(e0.x, w0.x, e0.y * w0.y);
        p = fmaf(e0.z, w0.z, p);
        p = fmaf(e0.w, w0.w, p);

        // reduce across the 32 lanes of the subgroup
        p += __shfl_xor(p, 1, 64);
        p += __shfl_xor(p, 2, 64);
        p += __shfl_xor(p, 4, 64);
        p += __shfl_xor(p, 8, 64);
        p += __shfl_xor(p, 16, 64);

        const float s = p + bias[node];
        loss += fmaxf(s, 0.0f) - s * t + __logf(1.0f + __expf(-fabsf(s)));
    }

    // combine the 2 subgroups of the wave (values uniform within subgroup)
    loss += __shfl_xor(loss, 32, 64);

    __shared__ float red[4];
    if (lane == 0) red[wid] = loss;
    __syncthreads();
    if (threadIdx.x == 0)
        partial[blockIdx.x] = (red[0] + red[1]) + (red[2] + red[3]);
}

__global__ __launch_bounds__(256) void hsm_reduce(
    const float* __restrict__ partial,
    float*       __restrict__ out)
{
    float s = 0.0f;
    for (int i = threadIdx.x; i < NBLK; i += 256) s += partial[i];
    #pragma unroll
    for (int off = 32; off >= 1; off >>= 1)
        s += __shfl_xor(s, off, 64);

    __shared__ float red[4];
    const int lane = threadIdx.x & 63, wid = threadIdx.x >> 6;
    if (lane == 0) red[wid] = s;
    __syncthreads();
    if (threadIdx.x == 0)
        out[0] = ((red[0] + red[1]) + (red[2] + red[3])) * (1.0f / (float)B);
}

extern "C" void kernel_launch(void* const* d_in, const int* in_sizes, int n_in,
                              void* d_out, int out_size, void* d_ws, size_t ws_size,
                              hipStream_t stream) {
    const float* emb  = (const float*)d_in[0];   // [B,E] f32
    const int*   widx = (const int*)  d_in[1];   // [B]   i32
    const float* W    = (const float*)d_in[2];   // [V-1,E] f32
    const float* bias = (const float*)d_in[3];   // [V-1] f32
    float* out     = (float*)d_out;
    float* partial = (float*)d_ws;               // NBLK floats, fully overwritten

    hsm_main<<<NBLK, 256, 0, stream>>>(emb, widx, W, bias, partial);
    hsm_reduce<<<1, 256, 0, stream>>>(partial, out);
}

// Round 7
// 107.652 us; speedup vs baseline: 1.0411x; 1.0411x over previous
//
#include <hip/hip_runtime.h>
#include <math.h>

// Problem constants (match reference)
constexpr int V = 131072;   // vocab / leaves
constexpr int D = 17;       // tree depth
constexpr int B = 16384;    // batch
constexpr int E = 128;      // embedding dim

constexpr int LPG  = 16;                  // lanes per (sample) group
constexpr int SPB  = 16;                  // samples per block (256 threads / 16)
constexpr int NBLK = B / SPB;             // 1024 blocks

// Best measured configuration (R3, 107.8 us total; main kernel ~17 us).
// 16 lanes cooperate on one sample; a wave holds 4 samples; loop over the 17
// tree levels with the embedding row register-cached. W row reads are two
// 256B fully-coalesced group loads. The kernel runs at the DRAM random-gather
// ceiling: FETCH ~33 MB (unique-row floor) served cold (the harness's 268 MB
// ws poison sweeps L3 every replay) at ~2 TB/s effective — occupancy (R6),
// level-split (R4), and batched-ILP (R5) variants all regressed or tied.
__global__ __launch_bounds__(256) void hsm_main(
    const float* __restrict__ emb,
    const int*   __restrict__ widx,
    const float* __restrict__ W,
    const float* __restrict__ bias,
    float*       __restrict__ partial)
{
    const int lane = threadIdx.x & 63;
    const int wid  = threadIdx.x >> 6;
    const int g    = lane >> 4;            // subgroup 0..3 within wave
    const int l    = lane & 15;            // lane within subgroup
    const int b    = blockIdx.x * SPB + wid * 4 + g;

    // embedding row: 16 lanes x 2 float4 = 512 B, register-cached for all 17 levels
    const float4* er = (const float4*)(emb + (size_t)b * E);
    const float4 e0 = er[l];
    const float4 e1 = er[l + LPG];

    const int j0 = widx[b] + V;            // 1-indexed leaf in heap layout

    float loss = 0.0f;
    #pragma unroll
    for (int d = 0; d < D; ++d) {
        const int   jc   = j0 >> d;        // 1-indexed child at this step
        const int   node = (jc >> 1) - 1;  // 0-indexed parent (scored node)
        const float t    = (float)(1 - (jc & 1));

        const float4* wr = (const float4*)(W + (size_t)node * E);
        const float4 w0 = wr[l];
        const float4 w1 = wr[l + LPG];

        float p;
        p = fmaf(e0.x, w0.x, e0.y * w0.y);
        p = fmaf(e0.z, w0.z, p);
        p = fmaf(e0.w, w0.w, p);
        p = fmaf(e1.x, w1.x, p);
        p = fmaf(e1.y, w1.y, p);
        p = fmaf(e1.z, w1.z, p);
        p = fmaf(e1.w, w1.w, p);

        // reduce across the 16 lanes of the subgroup
        p += __shfl_xor(p, 1, 64);
        p += __shfl_xor(p, 2, 64);
        p += __shfl_xor(p, 4, 64);
        p += __shfl_xor(p, 8, 64);

        const float s = p + bias[node];
        loss += fmaxf(s, 0.0f) - s * t + __logf(1.0f + __expf(-fabsf(s)));
    }

    // combine the 4 subgroups of the wave (each lane holds its group's sum)
    loss += __shfl_xor(loss, 16, 64);
    loss += __shfl_xor(loss, 32, 64);

    __shared__ float red[4];
    if (lane == 0) red[wid] = loss;
    __syncthreads();
    if (threadIdx.x == 0)
        partial[blockIdx.x] = (red[0] + red[1]) + (red[2] + red[3]);
}

__global__ __launch_bounds__(256) void hsm_reduce(
    const float* __restrict__ partial,
    float*       __restrict__ out)
{
    float s = 0.0f;
    for (int i = threadIdx.x; i < NBLK; i += 256) s += partial[i];
    #pragma unroll
    for (int off = 32; off >= 1; off >>= 1)
        s += __shfl_xor(s, off, 64);

    __shared__ float red[4];
    const int lane = threadIdx.x & 63, wid = threadIdx.x >> 6;
    if (lane == 0) red[wid] = s;
    __syncthreads();
    if (threadIdx.x == 0)
        out[0] = ((red[0] + red[1]) + (red[2] + red[3])) * (1.0f / (float)B);
}

extern "C" void kernel_launch(void* const* d_in, const int* in_sizes, int n_in,
                              void* d_out, int out_size, void* d_ws, size_t ws_size,
                              hipStream_t stream) {
    const float* emb  = (const float*)d_in[0];   // [B,E] f32
    const int*   widx = (const int*)  d_in[1];   // [B]   i32
    const float* W    = (const float*)d_in[2];   // [V-1,E] f32
    const float* bias = (const float*)d_in[3];   // [V-1] f32
    float* out     = (float*)d_out;
    float* partial = (float*)d_ws;               // NBLK floats, fully overwritten

    hsm_main<<<NBLK, 256, 0, stream>>>(emb, widx, W, bias, partial);
    hsm_reduce<<<1, 256, 0, stream>>>(partial, out);
}